// Round 1
// baseline (412.472 us; speedup 1.0000x reference)
//
#include <hip/hip_runtime.h>
#include <hip/hip_bf16.h>

constexpr int Bb = 2;
constexpr int Nn = 2048;
constexpr int Cc = 256;
constexpr int Hh = 16;
constexpr int Dd = 16;
constexpr int BN = Bb * Nn;   // 4096
constexpr int BH = Bb * Hh;   // 32
constexpr int D2 = Dd * Dd;   // 256

struct W7 {
    const float* W[7];
    const float* b[7];
};

// ---------------- Kernel 1: fused 7 residual linears -----------------
// Y[t][row][c] = (x[row][c] + sum_k x[row][k] * W_t[c][k] + b_t[c]) * mask[row] * (t>=3 ? scale : 1)
__global__ __launch_bounds__(256) void k_lin7(
    const float* __restrict__ x, const float* __restrict__ mask,
    W7 p, float scale, float* __restrict__ Y)
{
    const int col0 = blockIdx.x * 64;   // 0..1791 global output col
    const int row0 = blockIdx.y * 64;
    const int t = col0 >> 8;            // which linear (tile never straddles)
    const int wcol0 = col0 & 255;
    const float* __restrict__ W = p.W[t];
    const float* __restrict__ bias = p.b[t];
    const int tid = threadIdx.x;
    const int tx = tid & 15, ty = tid >> 4;

    __shared__ float Xt[32][65];
    __shared__ float Wt[32][65];

    float acc[4][4];
#pragma unroll
    for (int a = 0; a < 4; a++)
#pragma unroll
        for (int b = 0; b < 4; b++) acc[a][b] = 0.f;

    for (int k0 = 0; k0 < Cc; k0 += 32) {
#pragma unroll
        for (int rep = 0; rep < 2; rep++) {
            int fi = tid + rep * 256;       // 0..511
            int r = fi >> 3, c4 = fi & 7;   // 64 rows x 8 float4
            float4 vx = *reinterpret_cast<const float4*>(&x[(row0 + r) * Cc + k0 + c4 * 4]);
            Xt[c4 * 4 + 0][r] = vx.x; Xt[c4 * 4 + 1][r] = vx.y;
            Xt[c4 * 4 + 2][r] = vx.z; Xt[c4 * 4 + 3][r] = vx.w;
            float4 vw = *reinterpret_cast<const float4*>(&W[(wcol0 + r) * Cc + k0 + c4 * 4]);
            Wt[c4 * 4 + 0][r] = vw.x; Wt[c4 * 4 + 1][r] = vw.y;
            Wt[c4 * 4 + 2][r] = vw.z; Wt[c4 * 4 + 3][r] = vw.w;
        }
        __syncthreads();
#pragma unroll
        for (int kk = 0; kk < 32; kk++) {
            float av[4], bv[4];
#pragma unroll
            for (int a = 0; a < 4; a++) av[a] = Xt[kk][ty + 16 * a];
#pragma unroll
            for (int b = 0; b < 4; b++) bv[b] = Wt[kk][tx + 16 * b];
#pragma unroll
            for (int a = 0; a < 4; a++)
#pragma unroll
                for (int b = 0; b < 4; b++) acc[a][b] = fmaf(av[a], bv[b], acc[a][b]);
        }
        __syncthreads();
    }

    const float sc = (t >= 3) ? scale : 1.0f;
#pragma unroll
    for (int a = 0; a < 4; a++) {
        int row = row0 + ty + 16 * a;
        float m = mask[row] * sc;
#pragma unroll
        for (int b = 0; b < 4; b++) {
            int c = wcol0 + tx + 16 * b;
            float y = (acc[a][b] + x[row * Cc + c] + bias[c]) * m;
            Y[(size_t)t * BN * Cc + row * Cc + c] = y;
        }
    }
}

// ---------------- Kernel 2: state GEMM ------------------------------
// state[bh][ij][kl] = sum_n (k1[n,i]*v[n,j]) * (k2[n,k]*k3[n,l])
__global__ __launch_bounds__(256) void k_state(
    const float* __restrict__ Y, float* __restrict__ state)
{
    const int c0 = blockIdx.x * 64;   // kl tile
    const int r0 = blockIdx.y * 64;   // ij tile
    const int bh = blockIdx.z;
    const int b = bh >> 4, h = bh & 15;
    const int tid = threadIdx.x;
    const int tx = tid & 15, ty = tid >> 4;

    const float* __restrict__ k1 = Y + (size_t)3 * BN * Cc + (size_t)b * Nn * Cc + h * Dd;
    const float* __restrict__ vv = Y + (size_t)6 * BN * Cc + (size_t)b * Nn * Cc + h * Dd;
    const float* __restrict__ k2 = Y + (size_t)4 * BN * Cc + (size_t)b * Nn * Cc + h * Dd;
    const float* __restrict__ k3 = Y + (size_t)5 * BN * Cc + (size_t)b * Nn * Cc + h * Dd;

    __shared__ float raw[4][32][17];  // [k1,v,k2,k3][n][d]
    __shared__ float Pt[32][66];
    __shared__ float Qt[32][66];

    float acc[4][4];
#pragma unroll
    for (int a = 0; a < 4; a++)
#pragma unroll
        for (int b2 = 0; b2 < 4; b2++) acc[a][b2] = 0.f;

    for (int n0 = 0; n0 < Nn; n0 += 32) {
#pragma unroll
        for (int rep = 0; rep < 2; rep++) {
            int li = tid + rep * 256;          // 0..511 float4 index
            int tsr = li >> 7;                 // 0..3
            int within = li & 127;             // 32 rows * 4 f4
            int r = within >> 2, c4 = within & 3;
            const float* src = (tsr == 0) ? k1 : (tsr == 1) ? vv : (tsr == 2) ? k2 : k3;
            float4 v4 = *reinterpret_cast<const float4*>(&src[(n0 + r) * Cc + c4 * 4]);
            raw[tsr][r][c4 * 4 + 0] = v4.x; raw[tsr][r][c4 * 4 + 1] = v4.y;
            raw[tsr][r][c4 * 4 + 2] = v4.z; raw[tsr][r][c4 * 4 + 3] = v4.w;
        }
        __syncthreads();
        {
            int kk = tid >> 3;
            int base = (tid & 7) * 8;
#pragma unroll
            for (int e = 0; e < 8; e++) {
                int rl = base + e;
                int ij = r0 + rl;
                Pt[kk][rl] = raw[0][kk][ij >> 4] * raw[1][kk][ij & 15];
                int kl = c0 + rl;
                Qt[kk][rl] = raw[2][kk][kl >> 4] * raw[3][kk][kl & 15];
            }
        }
        __syncthreads();
#pragma unroll
        for (int kk = 0; kk < 32; kk++) {
            float av[4], bv[4];
#pragma unroll
            for (int a = 0; a < 4; a++) av[a] = Pt[kk][ty + 16 * a];
#pragma unroll
            for (int b2 = 0; b2 < 4; b2++) bv[b2] = Qt[kk][tx + 16 * b2];
#pragma unroll
            for (int a = 0; a < 4; a++)
#pragma unroll
                for (int b2 = 0; b2 < 4; b2++) acc[a][b2] = fmaf(av[a], bv[b2], acc[a][b2]);
        }
        __syncthreads();
    }

#pragma unroll
    for (int a = 0; a < 4; a++)
#pragma unroll
        for (int b2 = 0; b2 < 4; b2++)
            state[(size_t)bh * D2 * D2 + (r0 + ty + 16 * a) * D2 + (c0 + tx + 16 * b2)] = acc[a][b2];
}

// ---------------- Kernel 3: out1 GEMM + q1 contraction --------------
// T[n,ij] = sum_kl (q2[n,k]*q3[n,l]) * state[ij,kl];  out1[n, h*16+j] = sum_i q1[n,i]*T[n,i*16+j]
__global__ __launch_bounds__(256) void k_out1(
    const float* __restrict__ Y, const float* __restrict__ state,
    float* __restrict__ O1)
{
    const int n0 = blockIdx.x * 64;
    const int bh = blockIdx.y;
    const int b = bh >> 4, h = bh & 15;
    const int tid = threadIdx.x;
    const int tx = tid & 15, ty = tid >> 4;

    const float* __restrict__ q1 = Y + (size_t)0 * BN * Cc + (size_t)b * Nn * Cc + h * Dd;
    const float* __restrict__ q2 = Y + (size_t)1 * BN * Cc + (size_t)b * Nn * Cc + h * Dd;
    const float* __restrict__ q3 = Y + (size_t)2 * BN * Cc + (size_t)b * Nn * Cc + h * Dd;
    const float* __restrict__ S = state + (size_t)bh * D2 * D2;

    __shared__ float q1r[64][17], q2r[64][17], q3r[64][17];
    __shared__ float Ut[32][66];
    __shared__ float St[32][258];

    {
        int r = tid >> 2, c4 = tid & 3;    // 64 rows x 4 f4
        float4 a4 = *reinterpret_cast<const float4*>(&q1[(n0 + r) * Cc + c4 * 4]);
        q1r[r][c4 * 4 + 0] = a4.x; q1r[r][c4 * 4 + 1] = a4.y;
        q1r[r][c4 * 4 + 2] = a4.z; q1r[r][c4 * 4 + 3] = a4.w;
        float4 b4 = *reinterpret_cast<const float4*>(&q2[(n0 + r) * Cc + c4 * 4]);
        q2r[r][c4 * 4 + 0] = b4.x; q2r[r][c4 * 4 + 1] = b4.y;
        q2r[r][c4 * 4 + 2] = b4.z; q2r[r][c4 * 4 + 3] = b4.w;
        float4 c4v = *reinterpret_cast<const float4*>(&q3[(n0 + r) * Cc + c4 * 4]);
        q3r[r][c4 * 4 + 0] = c4v.x; q3r[r][c4 * 4 + 1] = c4v.y;
        q3r[r][c4 * 4 + 2] = c4v.z; q3r[r][c4 * 4 + 3] = c4v.w;
    }
    __syncthreads();

    float acc[4][16];
#pragma unroll
    for (int a = 0; a < 4; a++)
#pragma unroll
        for (int i = 0; i < 16; i++) acc[a][i] = 0.f;

    for (int kl0 = 0; kl0 < D2; kl0 += 32) {
        {
            const float* srow = &S[tid * D2 + kl0];
#pragma unroll
            for (int kq = 0; kq < 8; kq++) {
                float4 v4 = *reinterpret_cast<const float4*>(&srow[kq * 4]);
                St[kq * 4 + 0][tid] = v4.x; St[kq * 4 + 1][tid] = v4.y;
                St[kq * 4 + 2][tid] = v4.z; St[kq * 4 + 3][tid] = v4.w;
            }
        }
        {
            int kk = tid >> 3;
            int base = (tid & 7) * 8;
            int k = (kl0 + kk) >> 4, l = kk & 15;
#pragma unroll
            for (int e = 0; e < 8; e++) {
                int r = base + e;
                Ut[kk][r] = q2r[r][k] * q3r[r][l];
            }
        }
        __syncthreads();
#pragma unroll
        for (int kk = 0; kk < 32; kk++) {
            float av[4], bv[16];
#pragma unroll
            for (int a = 0; a < 4; a++) av[a] = Ut[kk][ty + 16 * a];
#pragma unroll
            for (int i = 0; i < 16; i++) bv[i] = St[kk][tx + 16 * i];
#pragma unroll
            for (int a = 0; a < 4; a++)
#pragma unroll
                for (int i = 0; i < 16; i++) acc[a][i] = fmaf(av[a], bv[i], acc[a][i]);
        }
        __syncthreads();
    }

#pragma unroll
    for (int a = 0; a < 4; a++) {
        int rl = ty + 16 * a;
        float sum = 0.f;
#pragma unroll
        for (int i = 0; i < 16; i++) sum = fmaf(q1r[rl][i], acc[a][i], sum);
        O1[((size_t)b * Nn + n0 + rl) * Cc + h * Dd + tx] = sum;
    }
}

// ---------------- Kernel 4: LayerNorm -------------------------------
__global__ __launch_bounds__(256) void k_ln(
    const float* __restrict__ O1, const float* __restrict__ gamma,
    const float* __restrict__ beta, float* __restrict__ Z)
{
    int row = blockIdx.x;
    int c = threadIdx.x;
    float v = O1[(size_t)row * Cc + c];
    float s = v, sq = v * v;
#pragma unroll
    for (int off = 32; off > 0; off >>= 1) {
        s += __shfl_down(s, off);
        sq += __shfl_down(sq, off);
    }
    __shared__ float ss[4], ssq[4];
    int wid = c >> 6, lane = c & 63;
    if (lane == 0) { ss[wid] = s; ssq[wid] = sq; }
    __syncthreads();
    s = ss[0] + ss[1] + ss[2] + ss[3];
    sq = ssq[0] + ssq[1] + ssq[2] + ssq[3];
    float mu = s * (1.f / 256.f);
    float var = sq * (1.f / 256.f) - mu * mu;
    float z = (v - mu) * rsqrtf(var + 1e-5f) * gamma[c] + beta[c];
    Z[(size_t)row * Cc + c] = z;
}

// ---------------- Kernel 5: final linear ----------------------------
__global__ __launch_bounds__(256) void k_final(
    const float* __restrict__ Z, const float* __restrict__ Wo,
    const float* __restrict__ bo, float* __restrict__ out)
{
    const int col0 = blockIdx.x * 64;
    const int row0 = blockIdx.y * 64;
    const int tid = threadIdx.x;
    const int tx = tid & 15, ty = tid >> 4;

    __shared__ float Xt[32][65];
    __shared__ float Wt[32][65];

    float acc[4][4];
#pragma unroll
    for (int a = 0; a < 4; a++)
#pragma unroll
        for (int b = 0; b < 4; b++) acc[a][b] = 0.f;

    for (int k0 = 0; k0 < Cc; k0 += 32) {
#pragma unroll
        for (int rep = 0; rep < 2; rep++) {
            int fi = tid + rep * 256;
            int r = fi >> 3, c4 = fi & 7;
            float4 vx = *reinterpret_cast<const float4*>(&Z[(row0 + r) * Cc + k0 + c4 * 4]);
            Xt[c4 * 4 + 0][r] = vx.x; Xt[c4 * 4 + 1][r] = vx.y;
            Xt[c4 * 4 + 2][r] = vx.z; Xt[c4 * 4 + 3][r] = vx.w;
            float4 vw = *reinterpret_cast<const float4*>(&Wo[(col0 + r) * Cc + k0 + c4 * 4]);
            Wt[c4 * 4 + 0][r] = vw.x; Wt[c4 * 4 + 1][r] = vw.y;
            Wt[c4 * 4 + 2][r] = vw.z; Wt[c4 * 4 + 3][r] = vw.w;
        }
        __syncthreads();
#pragma unroll
        for (int kk = 0; kk < 32; kk++) {
            float av[4], bv[4];
#pragma unroll
            for (int a = 0; a < 4; a++) av[a] = Xt[kk][ty + 16 * a];
#pragma unroll
            for (int b = 0; b < 4; b++) bv[b] = Wt[kk][tx + 16 * b];
#pragma unroll
            for (int a = 0; a < 4; a++)
#pragma unroll
                for (int b = 0; b < 4; b++) acc[a][b] = fmaf(av[a], bv[b], acc[a][b]);
        }
        __syncthreads();
    }

#pragma unroll
    for (int a = 0; a < 4; a++) {
        int row = row0 + ty + 16 * a;
#pragma unroll
        for (int b = 0; b < 4; b++) {
            int c = col0 + tx + 16 * b;
            out[(size_t)row * Cc + c] = acc[a][b] + bo[c];
        }
    }
}

extern "C" void kernel_launch(void* const* d_in, const int* in_sizes, int n_in,
                              void* d_out, int out_size, void* d_ws, size_t ws_size,
                              hipStream_t stream) {
    (void)in_sizes; (void)n_in; (void)out_size; (void)ws_size;
    const float* x    = (const float*)d_in[0];
    const float* mask = (const float*)d_in[1];
    W7 p;
    // order in dict: Wq1,bq1,Wq2,bq2,Wq3,bq3,Wk1,bk1,Wk2,bk2,Wk3,bk3,Wv,bv
    for (int t = 0; t < 7; t++) {
        p.W[t] = (const float*)d_in[2 + 2 * t];
        p.b[t] = (const float*)d_in[3 + 2 * t];
    }
    const float* Wo    = (const float*)d_in[16];
    const float* bo    = (const float*)d_in[17];
    const float* gamma = (const float*)d_in[18];
    const float* beta  = (const float*)d_in[19];

    float* ws    = (float*)d_ws;
    float* Y     = ws;                                   // 7*4096*256
    float* state = Y + (size_t)7 * BN * Cc;              // 32*256*256
    float* O1    = state + (size_t)BH * D2 * D2;         // 4096*256
    float* Z     = O1 + (size_t)BN * Cc;                 // 4096*256

    const float scale = 0.14865088937534013f;            // 2048^(-0.25)

    k_lin7 <<<dim3(28, 64), 256, 0, stream>>>(x, mask, p, scale, Y);
    k_state<<<dim3(4, 4, BH), 256, 0, stream>>>(Y, state);
    k_out1 <<<dim3(Nn / 64, BH), 256, 0, stream>>>(Y, state, O1);
    k_ln   <<<dim3(BN), 256, 0, stream>>>(O1, gamma, beta, Z);
    k_final<<<dim3(4, 64), 256, 0, stream>>>(Z, Wo, bo, (float*)d_out);
}

// Round 3
// 100.317 us; speedup vs baseline: 4.1117x; 4.1117x over previous
//
#include <hip/hip_runtime.h>
#include <hip/hip_bf16.h>

// ---------------------------------------------------------------------------
// QuadAttention MFMA implementation (f16 inputs, fp32 accum).
// Sizes: B=2, N=2048, C=256, H=16, D=16.  BN=4096, BH=32.
// ---------------------------------------------------------------------------

typedef _Float16 f16;
typedef _Float16 f16x8 __attribute__((ext_vector_type(8)));
typedef _Float16 f16x4 __attribute__((ext_vector_type(4)));
typedef float    f32x16 __attribute__((ext_vector_type(16)));

#define MFMA32(a, b, c) __builtin_amdgcn_mfma_f32_32x32x16_f16((a), (b), (c), 0, 0, 0)

constexpr int Nn = 2048, Cc = 256, BN = 4096, BH = 32;

// ws layout (bytes)
constexpr size_t OFF_XH  = 0;          // f16 [4096][256]
constexpr size_t OFF_WH  = 2097152;    // f16 [7][256][256]  (W+I, *scale for t>=3)
constexpr size_t OFF_BSC = 3014656;    // f32 [7][256]       (bias, *scale for t>=3)
constexpr size_t OFF_GH  = 3021824;    // f16 [256][256]     (Wo .* gamma)
constexpr size_t OFF_RSG = 3152896;    // f32 [256]          rowsum(G)
constexpr size_t OFF_B2  = 3153920;    // f32 [256]          beta@Wo^T + bo
constexpr size_t OFF_YQ  = 3154944;    // f16 [3][4096][256] q1,q2,q3
constexpr size_t OFF_KT  = 9446400;    // f16 [4][32][16][2048]  k1,k2,k3,v transposed per head
constexpr size_t OFF_SP  = 17835008;   // f32 [2][32][256][256] split-K partials
constexpr size_t OFF_SH  = 34612224;   // f16 [32][256][256] state
constexpr size_t OFF_O1  = 38806528;   // f32 [4096][256]
constexpr size_t OFF_MU  = 43000832;   // f32 [4096]
constexpr size_t OFF_RS  = 43017216;   // f32 [4096]

struct W7 { const float* W[7]; const float* b[7]; };

// Swizzled [R][64]-f16 tile helpers: rows are 128B = 8 granules of 16B;
// granule column XOR'ed with (row&7)  (T2 / G4 pattern, conflict-free b128).
__device__ __forceinline__ int toff(int row, int oct) {
    return row * 128 + (((oct) ^ (row & 7)) << 4);
}
__device__ __forceinline__ f16x8 ldfrag(const f16* base, int row, int oct) {
    return *(const f16x8*)((const char*)base + toff(row, oct));
}
__device__ __forceinline__ void stfrag(f16* base, int row, int oct, f16x8 v) {
    *(f16x8*)((char*)base + toff(row, oct)) = v;
}
// C/D layout of mfma_f32_32x32x16: col = lane&31, row = (reg&3)+8*(reg>>2)+4*(lane>>5)
__device__ __forceinline__ int drow(int reg, int l) {
    return (reg & 3) + ((reg >> 2) << 3) + ((l >> 5) << 2);
}
__device__ __forceinline__ void zero16(f32x16& v) {
#pragma unroll
    for (int i = 0; i < 16; ++i) v[i] = 0.f;
}

// ---------------- k_prep: f16 conversions, W+I, scale folding ---------------
__global__ __launch_bounds__(256) void k_prep(const float* __restrict__ x, W7 p,
                                              float scale, char* ws) {
    f16* xh  = (f16*)(ws + OFF_XH);
    f16* Wh  = (f16*)(ws + OFF_WH);
    float* bsc = (float*)(ws + OFF_BSC);
    int idx = blockIdx.x * 256 + threadIdx.x;
    if (idx < 262144) {                       // x -> xh (4 at a time)
        float4 v = ((const float4*)x)[idx];
        f16x4 o; o[0] = (f16)v.x; o[1] = (f16)v.y; o[2] = (f16)v.z; o[3] = (f16)v.w;
        *(f16x4*)(xh + (size_t)idx * 4) = o;
    } else if (idx < 262144 + 458752) {       // W' = (W + I) * (t>=3 ? scale : 1)
        int r = idx - 262144;
        int t = r >> 16, cc = r & 65535, c = cc >> 8, k = cc & 255;
        float v = p.W[t][cc] + (c == k ? 1.f : 0.f);
        if (t >= 3) v *= scale;
        Wh[r] = (f16)v;
    } else if (idx < 262144 + 458752 + 1792) { // scaled bias
        int r = idx - 262144 - 458752;
        int t = r >> 8;
        bsc[r] = p.b[t][r & 255] * (t >= 3 ? scale : 1.f);
    }
}

// ---------------- k_prep2: fold LN into final GEMM --------------------------
__global__ __launch_bounds__(256) void k_prep2(const float* __restrict__ Wo,
                                               const float* __restrict__ bo,
                                               const float* __restrict__ gamma,
                                               const float* __restrict__ beta,
                                               char* ws) {
    f16* Gh = (f16*)(ws + OFF_GH);
    float* rsg = (float*)(ws + OFF_RSG);
    float* B2  = (float*)(ws + OFF_B2);
    int c2 = blockIdx.x, c = threadIdx.x;
    float w = Wo[c2 * 256 + c];
    float g = gamma[c] * w;
    float bb = beta[c] * w;
    Gh[c2 * 256 + c] = (f16)g;
    __shared__ float sg[4], sb[4];
#pragma unroll
    for (int off = 32; off > 0; off >>= 1) { g += __shfl_down(g, off); bb += __shfl_down(bb, off); }
    if ((c & 63) == 0) { sg[c >> 6] = g; sb[c >> 6] = bb; }
    __syncthreads();
    if (c == 0) {
        rsg[c2] = sg[0] + sg[1] + sg[2] + sg[3];
        B2[c2]  = sb[0] + sb[1] + sb[2] + sb[3] + bo[c2];
    }
}

// ---------------- k_lin7: 7 fused linears via MFMA --------------------------
// t<3 : D[n][c] = xh @ W'^T  -> Yq[t] row-major
// t>=3: D[c][n] = W' @ xh^T  -> Kt[t-3][b][h][d][n]   (transposed for stage 2)
__global__ __launch_bounds__(256) void k_lin7(const float* __restrict__ mask, char* ws) {
    const f16* xh = (const f16*)(ws + OFF_XH);
    const f16* Wh = (const f16*)(ws + OFF_WH);
    const float* bsc = (const float*)(ws + OFF_BSC);
    f16* Yq = (f16*)(ws + OFF_YQ);
    f16* Kt = (f16*)(ws + OFF_KT);

    const int ct = blockIdx.x;            // 0..13
    const int rt = blockIdx.y;            // 0..31
    const int t = ct >> 1, half = ct & 1;
    const bool swap = (t >= 3);
    const int tid = threadIdx.x, l = tid & 63, w = tid >> 6;
    const int wr = w >> 1, wc = w & 1;

    __shared__ f16 Xl[128 * 64];
    __shared__ f16 Wl[128 * 64];

    f32x16 acc[2][2];
#pragma unroll
    for (int m = 0; m < 2; ++m)
#pragma unroll
        for (int mc = 0; mc < 2; ++mc) zero16(acc[m][mc]);

    const f16* Wt = Wh + (size_t)t * 65536;
    for (int kt = 0; kt < 4; ++kt) {
        __syncthreads();
        // stage both 128x64 tiles (reg route, swizzled)
#pragma unroll
        for (int e = 0; e < 4; ++e) {
            int g = tid + 256 * e;        // 0..1023
            int row = g >> 3, oct = g & 7;
            f16x8 vx = *(const f16x8*)(xh + (size_t)(rt * 128 + row) * 256 + kt * 64 + oct * 8);
            stfrag(Xl, row, oct, vx);
            f16x8 vw = *(const f16x8*)(Wt + (size_t)(half * 128 + row) * 256 + kt * 64 + oct * 8);
            stfrag(Wl, row, oct, vw);
        }
        __syncthreads();
        const f16* Ab = swap ? Wl : Xl;
        const f16* Bb = swap ? Xl : Wl;
#pragma unroll
        for (int s = 0; s < 4; ++s) {
            int g = s * 2 + (l >> 5);
            f16x8 a0 = ldfrag(Ab, wr * 64 + (l & 31), g);
            f16x8 a1 = ldfrag(Ab, wr * 64 + 32 + (l & 31), g);
            f16x8 b0 = ldfrag(Bb, wc * 64 + (l & 31), g);
            f16x8 b1 = ldfrag(Bb, wc * 64 + 32 + (l & 31), g);
            acc[0][0] = MFMA32(a0, b0, acc[0][0]);
            acc[0][1] = MFMA32(a0, b1, acc[0][1]);
            acc[1][0] = MFMA32(a1, b0, acc[1][0]);
            acc[1][1] = MFMA32(a1, b1, acc[1][1]);
        }
    }

#pragma unroll
    for (int m = 0; m < 2; ++m)
#pragma unroll
        for (int mc = 0; mc < 2; ++mc)
#pragma unroll
            for (int reg = 0; reg < 16; ++reg) {
                int rowl = wr * 64 + m * 32 + drow(reg, l);
                int coll = wc * 64 + mc * 32 + (l & 31);
                if (!swap) {
                    int n = rt * 128 + rowl;
                    int c = half * 128 + coll;
                    float v = (acc[m][mc][reg] + bsc[t * 256 + c]) * mask[n];
                    Yq[(size_t)t * 1048576 + (size_t)n * 256 + c] = (f16)v;
                } else {
                    int c = half * 128 + rowl;
                    int n = rt * 128 + coll;
                    float v = (acc[m][mc][reg] + bsc[t * 256 + c]) * mask[n];
                    int tn = t - 3, bb = n >> 11, h = c >> 4, d = c & 15;
                    Kt[(((size_t)tn * 32 + bb * 16 + h) * 16 + d) * 2048 + (n & 2047)] = (f16)v;
                }
            }
}

// ---------------- k_state: state = P^T Q  (split-K=2) -----------------------
__global__ __launch_bounds__(256) void k_state(char* ws) {
    const f16* Kt = (const f16*)(ws + OFF_KT);
    float* Sp = (float*)(ws + OFF_SP);

    const int tile = blockIdx.x;          // 0..3
    const int tr = tile >> 1, tc = tile & 1;
    const int bh = blockIdx.y;
    const int ks = blockIdx.z;            // 0..1
    const int tid = threadIdx.x, l = tid & 63, w = tid >> 6;
    const int wr = w >> 1, wc = w & 1;

    __shared__ f16 raw[4 * 16 * 64];      // 4 tensors x [16 d][64 n], swizzled
    __shared__ f16 Pt[128 * 64];          // [ij][n] swizzled
    __shared__ f16 Qt[128 * 64];          // [kl][n] swizzled

    f32x16 acc[2][2];
#pragma unroll
    for (int m = 0; m < 2; ++m)
#pragma unroll
        for (int mc = 0; mc < 2; ++mc) zero16(acc[m][mc]);

    // raw granule source: g in [0,512): t4=g>>7, d=(g>>3)&15, oct=g&7
    auto rsrc = [&](int g, int nb) -> const f16* {
        int t4 = g >> 7, d = (g >> 3) & 15, oct = g & 7;
        return Kt + (((size_t)t4 * 32 + bh) * 16 + d) * 2048 + nb + oct * 8;
    };

    f16x8 pre0 = *(const f16x8*)rsrc(tid, ks * 1024);
    f16x8 pre1 = *(const f16x8*)rsrc(tid + 256, ks * 1024);

    for (int kt = 0; kt < 16; ++kt) {
        {   // write prefetched raw
            int g0 = tid, g1 = tid + 256;
            stfrag(raw, (g0 >> 7) * 16 + ((g0 >> 3) & 15), g0 & 7, pre0);
            stfrag(raw, (g1 >> 7) * 16 + ((g1 >> 3) & 15), g1 & 7, pre1);
        }
        __syncthreads();
        // construct Pt (k1*v) and Qt (k2*k3).
        // Global ij = tr*128 + row  ->  i = tr*8 + (row>>4), j = row&15.
        // Global kl = tc*128 + row  ->  k = tc*8 + (row>>4), l = row&15.
#pragma unroll
        for (int s = 0; s < 2; ++s) {
            int gid = tid + 256 * s;          // 0..511
            int pq = gid >> 8, rem = gid & 255, oct = rem & 7, rg = rem >> 3;
            int ibase = ((pq == 0) ? tr : tc) * 8 + (rg >> 2);   // FIXED: global head-dim
            int tA = (pq == 0) ? 0 : 1;       // k1 : k2
            int tB = (pq == 0) ? 3 : 2;       // v  : k3
            f16x8 a = ldfrag(raw, tA * 16 + ibase, oct);
            f16* dst = (pq == 0) ? Pt : Qt;
#pragma unroll
            for (int jj = 0; jj < 4; ++jj) {
                int row = rg * 4 + jj;
                int j = row & 15;
                f16x8 b = ldfrag(raw, tB * 16 + j, oct);
                stfrag(dst, row, oct, a * b);
            }
        }
        __syncthreads();
        if (kt + 1 < 16) {                    // T14: prefetch next raw tile
            int nb = ks * 1024 + (kt + 1) * 64;
            pre0 = *(const f16x8*)rsrc(tid, nb);
            pre1 = *(const f16x8*)rsrc(tid + 256, nb);
        }
#pragma unroll
        for (int s = 0; s < 4; ++s) {
            int g = s * 2 + (l >> 5);
            f16x8 a0 = ldfrag(Pt, wr * 64 + (l & 31), g);
            f16x8 a1 = ldfrag(Pt, wr * 64 + 32 + (l & 31), g);
            f16x8 b0 = ldfrag(Qt, wc * 64 + (l & 31), g);
            f16x8 b1 = ldfrag(Qt, wc * 64 + 32 + (l & 31), g);
            acc[0][0] = MFMA32(a0, b0, acc[0][0]);
            acc[0][1] = MFMA32(a0, b1, acc[0][1]);
            acc[1][0] = MFMA32(a1, b0, acc[1][0]);
            acc[1][1] = MFMA32(a1, b1, acc[1][1]);
        }
    }

    float* outp = Sp + ((size_t)ks * 32 + bh) * 65536;
#pragma unroll
    for (int m = 0; m < 2; ++m)
#pragma unroll
        for (int mc = 0; mc < 2; ++mc)
#pragma unroll
            for (int reg = 0; reg < 16; ++reg) {
                int ij = tr * 128 + wr * 64 + m * 32 + drow(reg, l);
                int kl = tc * 128 + wc * 64 + mc * 32 + (l & 31);
                outp[ij * 256 + kl] = acc[m][mc][reg];
            }
}

// ---------------- k_sred: sum split-K partials -> f16 state ------------------
__global__ __launch_bounds__(256) void k_sred(char* ws) {
    const float* Sp = (const float*)(ws + OFF_SP);
    f16* Sh = (f16*)(ws + OFF_SH);
    int i = (blockIdx.x * 256 + threadIdx.x) * 4;
    float4 a = *(const float4*)(Sp + i);
    float4 b = *(const float4*)(Sp + 2097152 + i);
    f16x4 o;
    o[0] = (f16)(a.x + b.x); o[1] = (f16)(a.y + b.y);
    o[2] = (f16)(a.z + b.z); o[3] = (f16)(a.w + b.w);
    *(f16x4*)(Sh + i) = o;
}

// ---------------- k_out1: T = U @ S^T, fused q1 contraction ------------------
__global__ __launch_bounds__(256, 2) void k_out1(char* ws) {
    const f16* Yq = (const f16*)(ws + OFF_YQ);
    const f16* Sh = (const f16*)(ws + OFF_SH);
    float* O1 = (float*)(ws + OFF_O1);

    const int ntile = blockIdx.x;         // 0..15
    const int bh = blockIdx.y;
    const int b = bh >> 4, hb = (bh & 15) * 16;
    const int n0 = ntile * 128;
    const int tid = threadIdx.x, l = tid & 63, w = tid >> 6;
    const int wn = w >> 1, wc = w & 1;    // wave tile: 64 n x 128 ij

    const f16* q1h = Yq;
    const f16* q2h = Yq + 1048576;
    const f16* q3h = Yq + 2097152;

    __shared__ f16 Sl[256 * 64];          // state tile [ij][kl] swizzled (32KB)
    __shared__ f16 Ut[128 * 64];          // U tile [n][kl] swizzled
    __shared__ f16 q1l[128 * 16];         // q1 rows, linear
    float* part = (float*)Sl;             // epilogue overlay [4 waves][64][16]

    {   // stage q1 (one f16x8 per thread)
        int r = tid >> 1, hf = tid & 1;
        f16x8 v = *(const f16x8*)(q1h + (size_t)(b * 2048 + n0 + r) * 256 + hb + hf * 8);
        *(f16x8*)(q1l + r * 16 + hf * 8) = v;
    }

    f32x16 acc[2][4];
#pragma unroll
    for (int m = 0; m < 2; ++m)
#pragma unroll
        for (int fc = 0; fc < 4; ++fc) zero16(acc[m][fc]);

    for (int kt = 0; kt < 4; ++kt) {
        __syncthreads();
        const int kl0 = kt * 64;
#pragma unroll
        for (int e = 0; e < 8; ++e) {     // stage S tile
            int g = tid + 256 * e;        // 0..2047
            int row = g >> 3, oct = g & 7;
            f16x8 v = *(const f16x8*)(Sh + ((size_t)bh * 256 + row) * 256 + kl0 + oct * 8);
            stfrag(Sl, row, oct, v);
        }
#pragma unroll
        for (int e = 0; e < 4; ++e) {     // build U tile
            int g = tid + 256 * e;        // 0..1023
            int row = g >> 3, oct = g & 7;
            size_t nr = (size_t)(b * 2048 + n0 + row) * 256 + hb;
            f16 q2v = q2h[nr + ((kl0 + oct * 8) >> 4)];
            f16x8 q3v = *(const f16x8*)(q3h + nr + (oct & 1) * 8);
            stfrag(Ut, row, oct, q3v * q2v);
        }
        __syncthreads();
#pragma unroll
        for (int s = 0; s < 4; ++s) {
            int g = s * 2 + (l >> 5);
            f16x8 a0 = ldfrag(Ut, wn * 64 + (l & 31), g);
            f16x8 a1 = ldfrag(Ut, wn * 64 + 32 + (l & 31), g);
#pragma unroll
            for (int fc = 0; fc < 4; ++fc) {
                f16x8 bf = ldfrag(Sl, wc * 128 + fc * 32 + (l & 31), g);
                acc[0][fc] = MFMA32(a0, bf, acc[0][fc]);
                acc[1][fc] = MFMA32(a1, bf, acc[1][fc]);
            }
        }
    }

    __syncthreads();   // done with Sl as tiles; reuse as `part`
    const int hi = (l & 31) >> 4;
#pragma unroll
    for (int m = 0; m < 2; ++m)
#pragma unroll
        for (int reg = 0; reg < 16; ++reg) {
            float val = 0.f;
            int nloc = wn * 64 + m * 32 + drow(reg, l);
#pragma unroll
            for (int fc = 0; fc < 4; ++fc) {
                int iidx = 2 * fc + 8 * wc + hi;
                val += (float)q1l[nloc * 16 + iidx] * acc[m][fc][reg];
            }
            val += __shfl_xor(val, 16);
            if ((l & 16) == 0)
                part[((wn * 2 + wc) * 64 + m * 32 + drow(reg, l)) * 16 + (l & 15)] = val;
        }
    __syncthreads();
#pragma unroll
    for (int e = 0; e < 8; ++e) {
        int s = tid + 256 * e;            // 0..2047 -> (nloc, j)
        int j = s & 15, nloc = s >> 4;
        int wnb = nloc >> 6, nr = nloc & 63;
        float v = part[((wnb * 2 + 0) * 64 + nr) * 16 + j] +
                  part[((wnb * 2 + 1) * 64 + nr) * 16 + j];
        O1[(size_t)(b * 2048 + n0 + nloc) * 256 + hb + j] = v;
    }
}

// ---------------- k_stats: per-row LN stats ---------------------------------
__global__ __launch_bounds__(64) void k_stats(char* ws) {
    const float* O1 = (const float*)(ws + OFF_O1);
    float* mu = (float*)(ws + OFF_MU);
    float* rs = (float*)(ws + OFF_RS);
    int row = blockIdx.x, l = threadIdx.x;
    float4 v = *(const float4*)(O1 + (size_t)row * 256 + l * 4);
    float s = v.x + v.y + v.z + v.w;
    float sq = v.x * v.x + v.y * v.y + v.z * v.z + v.w * v.w;
#pragma unroll
    for (int off = 32; off > 0; off >>= 1) { s += __shfl_xor(s, off); sq += __shfl_xor(sq, off); }
    if (l == 0) {
        float m = s * (1.f / 256.f);
        float var = sq * (1.f / 256.f) - m * m;
        mu[row] = m;
        rs[row] = rsqrtf(var + 1e-5f);
    }
}

// ---------------- k_final: out = LN(O1) @ Wo^T + bo (LN folded) -------------
__global__ __launch_bounds__(256) void k_final(float* __restrict__ out, char* ws) {
    const float* O1 = (const float*)(ws + OFF_O1);
    const f16* Gh = (const f16*)(ws + OFF_GH);
    const float* rsg = (const float*)(ws + OFF_RSG);
    const float* B2 = (const float*)(ws + OFF_B2);
    const float* mu = (const float*)(ws + OFF_MU);
    const float* rs = (const float*)(ws + OFF_RS);

    const int ct = blockIdx.x;            // 0..1
    const int rt = blockIdx.y;            // 0..31
    const int tid = threadIdx.x, l = tid & 63, w = tid >> 6;
    const int wr = w >> 1, wc = w & 1;

    __shared__ f16 Xl[128 * 64];
    __shared__ f16 Wl[128 * 64];

    f32x16 acc[2][2];
#pragma unroll
    for (int m = 0; m < 2; ++m)
#pragma unroll
        for (int mc = 0; mc < 2; ++mc) zero16(acc[m][mc]);

    for (int kt = 0; kt < 4; ++kt) {
        __syncthreads();
#pragma unroll
        for (int e = 0; e < 4; ++e) {
            int g = tid + 256 * e;
            int row = g >> 3, oct = g & 7;
            const float* src = O1 + (size_t)(rt * 128 + row) * 256 + kt * 64 + oct * 8;
            float4 u0 = *(const float4*)src;
            float4 u1 = *(const float4*)(src + 4);
            f16x8 o;
            o[0] = (f16)u0.x; o[1] = (f16)u0.y; o[2] = (f16)u0.z; o[3] = (f16)u0.w;
            o[4] = (f16)u1.x; o[5] = (f16)u1.y; o[6] = (f16)u1.z; o[7] = (f16)u1.w;
            stfrag(Xl, row, oct, o);
            f16x8 vw = *(const f16x8*)(Gh + (size_t)(ct * 128 + row) * 256 + kt * 64 + oct * 8);
            stfrag(Wl, row, oct, vw);
        }
        __syncthreads();
#pragma unroll
        for (int s = 0; s < 4; ++s) {
            int g = s * 2 + (l >> 5);
            f16x8 a0 = ldfrag(Xl, wr * 64 + (l & 31), g);
            f16x8 a1 = ldfrag(Xl, wr * 64 + 32 + (l & 31), g);
            f16x8 b0 = ldfrag(Wl, wc * 64 + (l & 31), g);
            f16x8 b1 = ldfrag(Wl, wc * 64 + 32 + (l & 31), g);
            acc[0][0] = MFMA32(a0, b0, acc[0][0]);
            acc[0][1] = MFMA32(a0, b1, acc[0][1]);
            acc[1][0] = MFMA32(a1, b0, acc[1][0]);
            acc[1][1] = MFMA32(a1, b1, acc[1][1]);
        }
    }

#pragma unroll
    for (int m = 0; m < 2; ++m)
#pragma unroll
        for (int mc = 0; mc < 2; ++mc)
#pragma unroll
            for (int reg = 0; reg < 16; ++reg) {
                int n = rt * 128 + wr * 64 + m * 32 + drow(reg, l);
                int c2 = ct * 128 + wc * 64 + mc * 32 + (l & 31);
                float v = rs[n] * (acc[m][mc][reg] - mu[n] * rsg[c2]) + B2[c2];
                out[(size_t)n * 256 + c2] = v;
            }
}

// ---------------------------------------------------------------------------
extern "C" void kernel_launch(void* const* d_in, const int* in_sizes, int n_in,
                              void* d_out, int out_size, void* d_ws, size_t ws_size,
                              hipStream_t stream) {
    (void)in_sizes; (void)n_in; (void)out_size; (void)ws_size;
    const float* x    = (const float*)d_in[0];
    const float* mask = (const float*)d_in[1];
    W7 p;
    for (int t = 0; t < 7; ++t) {
        p.W[t] = (const float*)d_in[2 + 2 * t];
        p.b[t] = (const float*)d_in[3 + 2 * t];
    }
    const float* Wo    = (const float*)d_in[16];
    const float* bo    = (const float*)d_in[17];
    const float* gamma = (const float*)d_in[18];
    const float* beta  = (const float*)d_in[19];
    char* ws = (char*)d_ws;

    const float scale = 0.14865088937534013f;   // 2048^(-0.25)

    k_prep <<<2824, 256, 0, stream>>>(x, p, scale, ws);
    k_prep2<<<256, 256, 0, stream>>>(Wo, bo, gamma, beta, ws);
    k_lin7 <<<dim3(14, 32), 256, 0, stream>>>(mask, ws);
    k_state<<<dim3(4, 32, 2), 256, 0, stream>>>(ws);
    k_sred <<<2048, 256, 0, stream>>>(ws);
    k_out1 <<<dim3(16, 32), 256, 0, stream>>>(ws);
    k_stats<<<4096, 64, 0, stream>>>(ws);
    k_final<<<dim3(2, 32), 256, 0, stream>>>((float*)d_out, ws);
}

// Round 4
// 85.324 us; speedup vs baseline: 4.8342x; 1.1757x over previous
//
#include <hip/hip_runtime.h>
#include <hip/hip_bf16.h>

// ---------------------------------------------------------------------------
// QuadAttention MFMA implementation (f16 inputs, fp32 accum).
// Sizes: B=2, N=2048, C=256, H=16, D=16.  BN=4096, BH=32.
// ---------------------------------------------------------------------------

typedef _Float16 f16;
typedef _Float16 f16x8 __attribute__((ext_vector_type(8)));
typedef _Float16 f16x4 __attribute__((ext_vector_type(4)));
typedef float    f32x16 __attribute__((ext_vector_type(16)));

#define MFMA32(a, b, c) __builtin_amdgcn_mfma_f32_32x32x16_f16((a), (b), (c), 0, 0, 0)

constexpr int Nn = 2048, Cc = 256, BN = 4096, BH = 32;

// ws layout (bytes)
constexpr size_t OFF_XH  = 0;          // f16 [4096][256]
constexpr size_t OFF_WH  = 2097152;    // f16 [7][256][256]  (W+I, *scale for t>=3)
constexpr size_t OFF_BSC = 3014656;    // f32 [7][256]
constexpr size_t OFF_GH  = 3021824;    // f16 [256][256]     (Wo .* gamma)
constexpr size_t OFF_RSG = 3152896;    // f32 [256]
constexpr size_t OFF_B2  = 3153920;    // f32 [256]
constexpr size_t OFF_YQ  = 3154944;    // f16 [3][4096][256] q1,q2,q3
constexpr size_t OFF_KT  = 9446400;    // f16 [4][32][16][2048]  k1,k2,k3,v per-head transposed
constexpr size_t OFF_SP  = 17835008;   // f16 [4][32][256][256] split-K partials (16MB)
constexpr size_t OFF_SH  = 34612224;   // f16 [32][256][256] state
constexpr size_t OFF_O1  = 38806528;   // f16 [4096][256]

struct W7 { const float* W[7]; const float* b[7]; };

// Swizzled [R][64]-f16 tile helpers: rows are 128B = 8 granules of 16B;
// granule column XOR'ed with (row&7)  (T2 / G4 pattern, conflict-free b128).
__device__ __forceinline__ int toff(int row, int oct) {
    return row * 128 + (((oct) ^ (row & 7)) << 4);
}
__device__ __forceinline__ f16x8 ldfrag(const f16* base, int row, int oct) {
    return *(const f16x8*)((const char*)base + toff(row, oct));
}
__device__ __forceinline__ void stfrag(f16* base, int row, int oct, f16x8 v) {
    *(f16x8*)((char*)base + toff(row, oct)) = v;
}
// C/D layout of mfma_f32_32x32x16: col = lane&31, row = (reg&3)+8*(reg>>2)+4*(lane>>5)
__device__ __forceinline__ int drow(int reg, int l) {
    return (reg & 3) + ((reg >> 2) << 3) + ((l >> 5) << 2);
}
__device__ __forceinline__ void zero16(f32x16& v) {
#pragma unroll
    for (int i = 0; i < 16; ++i) v[i] = 0.f;
}

// ---------------- k_prep: conversions + W+I + scale + LN-fold prep ----------
__global__ __launch_bounds__(256) void k_prep(const float* __restrict__ x, W7 p,
                                              float scale,
                                              const float* __restrict__ Wo,
                                              const float* __restrict__ bo,
                                              const float* __restrict__ gamma,
                                              const float* __restrict__ beta,
                                              char* ws) {
    const int bid = blockIdx.x;
    if (bid < 2824) {
        f16* xh  = (f16*)(ws + OFF_XH);
        f16* Wh  = (f16*)(ws + OFF_WH);
        float* bsc = (float*)(ws + OFF_BSC);
        int idx = bid * 256 + threadIdx.x;
        if (idx < 262144) {                        // x -> xh
            float4 v = ((const float4*)x)[idx];
            f16x4 o; o[0] = (f16)v.x; o[1] = (f16)v.y; o[2] = (f16)v.z; o[3] = (f16)v.w;
            *(f16x4*)(xh + (size_t)idx * 4) = o;
        } else if (idx < 262144 + 458752) {        // W' = (W+I)*(t>=3?scale:1)
            int r = idx - 262144;
            int t = r >> 16, cc = r & 65535, c = cc >> 8, k = cc & 255;
            float v = p.W[t][cc] + (c == k ? 1.f : 0.f);
            if (t >= 3) v *= scale;
            Wh[r] = (f16)v;
        } else if (idx < 262144 + 458752 + 1792) { // scaled bias
            int r = idx - 262144 - 458752;
            int t = r >> 8;
            bsc[r] = p.b[t][r & 255] * (t >= 3 ? scale : 1.f);
        }
    } else {                                       // LN-fold (ex k_prep2)
        f16* Gh = (f16*)(ws + OFF_GH);
        float* rsg = (float*)(ws + OFF_RSG);
        float* B2  = (float*)(ws + OFF_B2);
        int c2 = bid - 2824, c = threadIdx.x;
        float wv = Wo[c2 * 256 + c];
        float g = gamma[c] * wv;
        float bb = beta[c] * wv;
        Gh[c2 * 256 + c] = (f16)g;
        __shared__ float sg[4], sb[4];
#pragma unroll
        for (int off = 32; off > 0; off >>= 1) { g += __shfl_down(g, off); bb += __shfl_down(bb, off); }
        if ((c & 63) == 0) { sg[c >> 6] = g; sb[c >> 6] = bb; }
        __syncthreads();
        if (c == 0) {
            rsg[c2] = sg[0] + sg[1] + sg[2] + sg[3];
            B2[c2]  = sb[0] + sb[1] + sb[2] + sb[3] + bo[c2];
        }
    }
}

// ---------------- k_lin7: 7 fused linears via MFMA --------------------------
// t<3 : D[n][c] = xh @ W'^T  -> Yq[t] row-major
// t>=3: D[c][n] = W' @ xh^T  -> Kt[t-3][b*16+h][d][n]
__global__ __launch_bounds__(256) void k_lin7(const float* __restrict__ mask, char* ws) {
    const f16* xh = (const f16*)(ws + OFF_XH);
    const f16* Wh = (const f16*)(ws + OFF_WH);
    const float* bsc = (const float*)(ws + OFF_BSC);
    f16* Yq = (f16*)(ws + OFF_YQ);
    f16* Kt = (f16*)(ws + OFF_KT);

    const int ct = blockIdx.x;            // 0..13
    const int rt = blockIdx.y;            // 0..31
    const int t = ct >> 1, half = ct & 1;
    const bool swap = (t >= 3);
    const int tid = threadIdx.x, l = tid & 63, w = tid >> 6;
    const int wr = w >> 1, wc = w & 1;

    __shared__ f16 Xl[128 * 64];
    __shared__ f16 Wl[128 * 64];

    f32x16 acc[2][2];
#pragma unroll
    for (int m = 0; m < 2; ++m)
#pragma unroll
        for (int mc = 0; mc < 2; ++mc) zero16(acc[m][mc]);

    const f16* Wt = Wh + (size_t)t * 65536;
    for (int kt = 0; kt < 4; ++kt) {
        __syncthreads();
#pragma unroll
        for (int e = 0; e < 4; ++e) {
            int g = tid + 256 * e;
            int row = g >> 3, oct = g & 7;
            f16x8 vx = *(const f16x8*)(xh + (size_t)(rt * 128 + row) * 256 + kt * 64 + oct * 8);
            stfrag(Xl, row, oct, vx);
            f16x8 vw = *(const f16x8*)(Wt + (size_t)(half * 128 + row) * 256 + kt * 64 + oct * 8);
            stfrag(Wl, row, oct, vw);
        }
        __syncthreads();
        const f16* Ab = swap ? Wl : Xl;
        const f16* Bb = swap ? Xl : Wl;
#pragma unroll
        for (int s = 0; s < 4; ++s) {
            int g = s * 2 + (l >> 5);
            f16x8 a0 = ldfrag(Ab, wr * 64 + (l & 31), g);
            f16x8 a1 = ldfrag(Ab, wr * 64 + 32 + (l & 31), g);
            f16x8 b0 = ldfrag(Bb, wc * 64 + (l & 31), g);
            f16x8 b1 = ldfrag(Bb, wc * 64 + 32 + (l & 31), g);
            acc[0][0] = MFMA32(a0, b0, acc[0][0]);
            acc[0][1] = MFMA32(a0, b1, acc[0][1]);
            acc[1][0] = MFMA32(a1, b0, acc[1][0]);
            acc[1][1] = MFMA32(a1, b1, acc[1][1]);
        }
    }

#pragma unroll
    for (int m = 0; m < 2; ++m)
#pragma unroll
        for (int mc = 0; mc < 2; ++mc)
#pragma unroll
            for (int reg = 0; reg < 16; ++reg) {
                int rowl = wr * 64 + m * 32 + drow(reg, l);
                int coll = wc * 64 + mc * 32 + (l & 31);
                if (!swap) {
                    int n = rt * 128 + rowl;
                    int c = half * 128 + coll;
                    float v = (acc[m][mc][reg] + bsc[t * 256 + c]) * mask[n];
                    Yq[(size_t)t * 1048576 + (size_t)n * 256 + c] = (f16)v;
                } else {
                    int c = half * 128 + rowl;
                    int n = rt * 128 + coll;
                    float v = (acc[m][mc][reg] + bsc[t * 256 + c]) * mask[n];
                    int tn = t - 3, bb = n >> 11, h = c >> 4, d = c & 15;
                    Kt[(((size_t)tn * 32 + bb * 16 + h) * 16 + d) * 2048 + (n & 2047)] = (f16)v;
                }
            }
}

// ---------------- k_state: state = P^T Q, register-direct P/Q ---------------
// Block: 128 ij (tr half) x 256 kl, split-K=4 (512 n each). f16 partials.
__global__ __launch_bounds__(256, 2) void k_state(char* ws) {
    const f16* Kt = (const f16*)(ws + OFF_KT);
    f16* Sp = (f16*)(ws + OFF_SP);

    const int tr = blockIdx.x;            // 0..1  ij half
    const int bh = blockIdx.y;            // 0..31
    const int ks = blockIdx.z;            // 0..3  split-K
    const int tid = threadIdx.x, l = tid & 63, w = tid >> 6;
    const int wr = w >> 1, wc = w & 1;    // wave tile: 64 ij x 128 kl

    __shared__ f16 raw[2][64 * 64];       // dbuf [k1|k2|k3|v][16 d][64 n] swizzled

    f32x16 acc[2][4];
#pragma unroll
    for (int m = 0; m < 2; ++m)
#pragma unroll
        for (int mc = 0; mc < 4; ++mc) zero16(acc[m][mc]);

    const int nb0 = ks * 512;
    auto gaddr = [&](int g, int nb) -> const f16x8* {
        int t4 = g >> 7, d = (g >> 3) & 15, oct = g & 7;
        return (const f16x8*)(Kt + (((size_t)t4 * 32 + bh) * 16 + d) * 2048 + nb + oct * 8);
    };
    const int rowA = (tid >> 7) * 16 + ((tid >> 3) & 15);   // t4 0..1
    const int rowB = rowA + 32;                             // t4 2..3
    const int octS = tid & 7;

    f16x8 pre0 = *gaddr(tid, nb0);
    f16x8 pre1 = *gaddr(tid + 256, nb0);
    stfrag(raw[0], rowA, octS, pre0);
    stfrag(raw[0], rowB, octS, pre1);
    __syncthreads();

    int cur = 0;
    for (int kt = 0; kt < 8; ++kt) {
        if (kt < 7) {
            pre0 = *gaddr(tid, nb0 + (kt + 1) * 64);
            pre1 = *gaddr(tid + 256, nb0 + (kt + 1) * 64);
        }
        const f16* rb = raw[cur];
#pragma unroll
        for (int s = 0; s < 4; ++s) {
            const int og = s * 2 + (l >> 5);
            f16x8 a[2], b[4];
#pragma unroll
            for (int m = 0; m < 2; ++m) {
                int rloc = wr * 64 + m * 32 + (l & 31);
                // P[ij] = k1[i] * v[j]: raw rows 0..15 = k1, 48..63 = v
                a[m] = ldfrag(rb, tr * 8 + (rloc >> 4), og) * ldfrag(rb, 48 + (rloc & 15), og);
            }
#pragma unroll
            for (int mc = 0; mc < 4; ++mc) {
                int cloc = wc * 128 + mc * 32 + (l & 31);
                // Q[kl] = k2[k] * k3[lv]: raw rows 16..31 = k2, 32..47 = k3
                b[mc] = ldfrag(rb, 16 + (cloc >> 4), og) * ldfrag(rb, 32 + (cloc & 15), og);
            }
#pragma unroll
            for (int m = 0; m < 2; ++m)
#pragma unroll
                for (int mc = 0; mc < 4; ++mc)
                    acc[m][mc] = MFMA32(a[m], b[mc], acc[m][mc]);
        }
        if (kt < 7) {
            stfrag(raw[cur ^ 1], rowA, octS, pre0);
            stfrag(raw[cur ^ 1], rowB, octS, pre1);
        }
        __syncthreads();
        cur ^= 1;
    }

    f16* outp = Sp + ((size_t)ks * 32 + bh) * 65536;
#pragma unroll
    for (int m = 0; m < 2; ++m)
#pragma unroll
        for (int mc = 0; mc < 4; ++mc)
#pragma unroll
            for (int reg = 0; reg < 16; ++reg) {
                int ij = tr * 128 + wr * 64 + m * 32 + drow(reg, l);
                int kl = wc * 128 + mc * 32 + (l & 31);
                outp[ij * 256 + kl] = (f16)acc[m][mc][reg];
            }
}

// ---------------- k_sred: sum 4 f16 split-K partials -> f16 state -----------
__global__ __launch_bounds__(256) void k_sred(char* ws) {
    const f16x8* Sp = (const f16x8*)(ws + OFF_SP);
    f16x8* Sh = (f16x8*)(ws + OFF_SH);
    int i = blockIdx.x * 256 + threadIdx.x;     // granule index, 262144 total
    f16x8 a = Sp[i], b = Sp[262144 + i], c = Sp[524288 + i], d = Sp[786432 + i];
    Sh[i] = (a + b) + (c + d);
}

// ---------------- k_out1: T = U @ S^T (register-direct U) + q1 contraction --
__global__ __launch_bounds__(256, 2) void k_out1(char* ws) {
    const f16* Yq = (const f16*)(ws + OFF_YQ);
    const f16* Sh = (const f16*)(ws + OFF_SH);
    f16* O1 = (f16*)(ws + OFF_O1);

    const int ntile = blockIdx.x;         // 0..15
    const int bh = blockIdx.y;
    const int b = bh >> 4, hb = (bh & 15) * 16;
    const int n0 = ntile * 128;
    const int tid = threadIdx.x, l = tid & 63, w = tid >> 6;
    const int wn = w >> 1, wc = w & 1;    // wave tile: 64 n x 128 ij

    __shared__ f16 Sl[2][256 * 64];       // state tile dbuf (64KB)
    __shared__ f16 Ql[128 * 64];          // per row: [q1 0-15][q2 16-31][q3 32-47][pad]
    float* part = (float*)Sl;             // epilogue overlay [4][64][16] f32

    // stage Ql (octs 0..5 hold q1,q2,q3; 6,7 unused)
#pragma unroll
    for (int e = 0; e < 4; ++e) {
        int g = tid + 256 * e;
        int row = g >> 3, oct = g & 7;
        if (oct < 6) {
            int t = oct >> 1, hf = oct & 1;
            f16x8 v = *(const f16x8*)(Yq + (size_t)t * 1048576 +
                                      (size_t)(b * 2048 + n0 + row) * 256 + hb + hf * 8);
            stfrag(Ql, row, oct, v);
        }
    }
    // stage Sl[0]
    const int qrow = tid >> 3, qoct = tid & 7;
    f16x8 pre[8];
#pragma unroll
    for (int e = 0; e < 8; ++e)
        pre[e] = *(const f16x8*)(Sh + (size_t)bh * 65536 + (size_t)(qrow + 32 * e) * 256 + qoct * 8);
#pragma unroll
    for (int e = 0; e < 8; ++e) stfrag(Sl[0], qrow + 32 * e, qoct, pre[e]);
    __syncthreads();

    f32x16 acc[2][4];
#pragma unroll
    for (int m = 0; m < 2; ++m)
#pragma unroll
        for (int fc = 0; fc < 4; ++fc) zero16(acc[m][fc]);

    int cur = 0;
    for (int kt = 0; kt < 4; ++kt) {
        if (kt < 3) {
#pragma unroll
            for (int e = 0; e < 8; ++e)
                pre[e] = *(const f16x8*)(Sh + (size_t)bh * 65536 +
                                         (size_t)(qrow + 32 * e) * 256 + (kt + 1) * 64 + qoct * 8);
        }
        const f16* sb = Sl[cur];
#pragma unroll
        for (int s = 0; s < 4; ++s) {
            const int og = s * 2 + (l >> 5);
            const int kq = kt * 4 + s;        // global q2 column (= (kt*64+og*8)>>4)
            f16x8 a[2];
#pragma unroll
            for (int m = 0; m < 2; ++m) {
                int nloc = wn * 64 + m * 32 + (l & 31);
                f16x8 q3 = ldfrag(Ql, nloc, 4 + (og & 1));
                f16 q2 = *(const f16*)((const char*)Ql + toff(nloc, 2 + (kq >> 3)) + (kq & 7) * 2);
                a[m] = q3 * q2;
            }
#pragma unroll
            for (int fc = 0; fc < 4; ++fc) {
                f16x8 bf = ldfrag(sb, wc * 128 + fc * 32 + (l & 31), og);
                acc[0][fc] = MFMA32(a[0], bf, acc[0][fc]);
                acc[1][fc] = MFMA32(a[1], bf, acc[1][fc]);
            }
        }
        if (kt < 3) {
#pragma unroll
            for (int e = 0; e < 8; ++e) stfrag(Sl[cur ^ 1], qrow + 32 * e, qoct, pre[e]);
        }
        __syncthreads();
        cur ^= 1;
    }

    // epilogue: out[n][j] = sum_i q1[n][i] * T[n][i*16+j]
    const int hi = (l & 31) >> 4;
#pragma unroll
    for (int m = 0; m < 2; ++m)
#pragma unroll
        for (int reg = 0; reg < 16; ++reg) {
            int nloc = wn * 64 + m * 32 + drow(reg, l);
            f16x8 q1v = ldfrag(Ql, nloc, wc);     // q1 elems [8*wc .. 8*wc+8)
            float val = 0.f;
#pragma unroll
            for (int fc = 0; fc < 4; ++fc) {
                float qv = hi ? (float)q1v[2 * fc + 1] : (float)q1v[2 * fc];
                val += qv * acc[m][fc][reg];
            }
            val += __shfl_xor(val, 16);
            if ((l & 16) == 0)
                part[((wn * 2 + wc) * 64 + (nloc & 63)) * 16 + (l & 15)] = val;
        }
    __syncthreads();
    {
        int nloc = tid >> 1, jb = (tid & 1) * 8;
        int wnb = nloc >> 6, nr = nloc & 63;
        f16x8 o;
#pragma unroll
        for (int e = 0; e < 8; ++e) {
            int j = jb + e;
            o[e] = (f16)(part[((wnb * 2 + 0) * 64 + nr) * 16 + j] +
                         part[((wnb * 2 + 1) * 64 + nr) * 16 + j]);
        }
        *(f16x8*)(O1 + (size_t)(b * 2048 + n0 + nloc) * 256 + hb + jb) = o;
    }
}

// ---------------- k_final: out = LN(O1) @ Wo^T + bo, stats fused ------------
__global__ __launch_bounds__(256) void k_final(float* __restrict__ out, char* ws) {
    const f16* O1 = (const f16*)(ws + OFF_O1);
    const f16* Gh = (const f16*)(ws + OFF_GH);
    const float* rsg = (const float*)(ws + OFF_RSG);
    const float* B2 = (const float*)(ws + OFF_B2);

    const int ct = blockIdx.x;            // 0..1
    const int rt = blockIdx.y;            // 0..31
    const int tid = threadIdx.x, l = tid & 63, w = tid >> 6;
    const int wr = w >> 1, wc = w & 1;

    __shared__ f16 Xl[128 * 64];
    __shared__ f16 Wl[128 * 64];
    __shared__ float muL[128], rsL[128];

    float sum[4] = {0.f, 0.f, 0.f, 0.f}, sumsq[4] = {0.f, 0.f, 0.f, 0.f};

    f32x16 acc[2][2];
#pragma unroll
    for (int m = 0; m < 2; ++m)
#pragma unroll
        for (int mc = 0; mc < 2; ++mc) zero16(acc[m][mc]);

    for (int kt = 0; kt < 4; ++kt) {
        __syncthreads();
#pragma unroll
        for (int e = 0; e < 4; ++e) {
            int g = tid + 256 * e;
            int row = g >> 3, oct = g & 7;
            f16x8 vx = *(const f16x8*)(O1 + (size_t)(rt * 128 + row) * 256 + kt * 64 + oct * 8);
            stfrag(Xl, row, oct, vx);
#pragma unroll
            for (int q = 0; q < 8; ++q) { float f = (float)vx[q]; sum[e] += f; sumsq[e] += f * f; }
            f16x8 vw = *(const f16x8*)(Gh + (size_t)(ct * 128 + row) * 256 + kt * 64 + oct * 8);
            stfrag(Wl, row, oct, vw);
        }
        __syncthreads();
#pragma unroll
        for (int s = 0; s < 4; ++s) {
            int g = s * 2 + (l >> 5);
            f16x8 a0 = ldfrag(Xl, wr * 64 + (l & 31), g);
            f16x8 a1 = ldfrag(Xl, wr * 64 + 32 + (l & 31), g);
            f16x8 b0 = ldfrag(Wl, wc * 64 + (l & 31), g);
            f16x8 b1 = ldfrag(Wl, wc * 64 + 32 + (l & 31), g);
            acc[0][0] = MFMA32(a0, b0, acc[0][0]);
            acc[0][1] = MFMA32(a0, b1, acc[0][1]);
            acc[1][0] = MFMA32(a1, b0, acc[1][0]);
            acc[1][1] = MFMA32(a1, b1, acc[1][1]);
        }
    }

    // row stats: 8 threads (same tid>>3) share each row
#pragma unroll
    for (int e = 0; e < 4; ++e) {
#pragma unroll
        for (int off = 1; off < 8; off <<= 1) {
            sum[e] += __shfl_xor(sum[e], off);
            sumsq[e] += __shfl_xor(sumsq[e], off);
        }
    }
    if ((tid & 7) == 0) {
#pragma unroll
        for (int e = 0; e < 4; ++e) {
            int row = (tid >> 3) + 32 * e;
            float m = sum[e] * (1.f / 256.f);
            float var = sumsq[e] * (1.f / 256.f) - m * m;
            muL[row] = m;
            rsL[row] = rsqrtf(var + 1e-5f);
        }
    }
    __syncthreads();

#pragma unroll
    for (int m = 0; m < 2; ++m)
#pragma unroll
        for (int mc = 0; mc < 2; ++mc)
#pragma unroll
            for (int reg = 0; reg < 16; ++reg) {
                int nloc = wr * 64 + m * 32 + drow(reg, l);
                int n = rt * 128 + nloc;
                int c2 = ct * 128 + wc * 64 + mc * 32 + (l & 31);
                float v = rsL[nloc] * (acc[m][mc][reg] - muL[nloc] * rsg[c2]) + B2[c2];
                out[(size_t)n * 256 + c2] = v;
            }
}

// ---------------------------------------------------------------------------
extern "C" void kernel_launch(void* const* d_in, const int* in_sizes, int n_in,
                              void* d_out, int out_size, void* d_ws, size_t ws_size,
                              hipStream_t stream) {
    (void)in_sizes; (void)n_in; (void)out_size; (void)ws_size;
    const float* x    = (const float*)d_in[0];
    const float* mask = (const float*)d_in[1];
    W7 p;
    for (int t = 0; t < 7; ++t) {
        p.W[t] = (const float*)d_in[2 + 2 * t];
        p.b[t] = (const float*)d_in[3 + 2 * t];
    }
    const float* Wo    = (const float*)d_in[16];
    const float* bo    = (const float*)d_in[17];
    const float* gamma = (const float*)d_in[18];
    const float* beta  = (const float*)d_in[19];
    char* ws = (char*)d_ws;

    const float scale = 0.14865088937534013f;   // 2048^(-0.25)

    k_prep <<<3080, 256, 0, stream>>>(x, p, scale, Wo, bo, gamma, beta, ws);
    k_lin7 <<<dim3(14, 32), 256, 0, stream>>>(mask, ws);
    k_state<<<dim3(2, 32, 4), 256, 0, stream>>>(ws);
    k_sred <<<1024, 256, 0, stream>>>(ws);
    k_out1 <<<dim3(16, 32), 256, 0, stream>>>(ws);
    k_final<<<dim3(2, 32), 256, 0, stream>>>((float*)d_out, ws);
}

// Round 5
// 80.296 us; speedup vs baseline: 5.1369x; 1.0626x over previous
//
#include <hip/hip_runtime.h>
#include <hip/hip_bf16.h>

// ---------------------------------------------------------------------------
// QuadAttention MFMA implementation (f16 inputs, fp32 accum).
// Sizes: B=2, N=2048, C=256, H=16, D=16.  BN=4096, BH=32.
// ---------------------------------------------------------------------------

typedef _Float16 f16;
typedef _Float16 f16x8 __attribute__((ext_vector_type(8)));
typedef _Float16 f16x4 __attribute__((ext_vector_type(4)));
typedef float    f32x16 __attribute__((ext_vector_type(16)));

#define MFMA32(a, b, c) __builtin_amdgcn_mfma_f32_32x32x16_f16((a), (b), (c), 0, 0, 0)

constexpr int Nn = 2048, Cc = 256, BN = 4096, BH = 32;

// ws layout (bytes)
constexpr size_t OFF_XH  = 0;          // f16 [4096][256]
constexpr size_t OFF_WH  = 2097152;    // f16 [7][256][256]  (W+I, *scale for t>=3)
constexpr size_t OFF_BSC = 3014656;    // f32 [7][256]
constexpr size_t OFF_GH  = 3021824;    // f16 [256][256]     (Wo .* gamma)
constexpr size_t OFF_RSG = 3152896;    // f32 [256]
constexpr size_t OFF_B2  = 3153920;    // f32 [256]
constexpr size_t OFF_YQ  = 3154944;    // f16 [3][4096][256] q1,q2,q3
constexpr size_t OFF_KT  = 9446400;    // f16 [4][32][16][2048]  k1,k2,k3,v per-head transposed
constexpr size_t OFF_SP  = 17835008;   // f16 [4][32][256][256] split-K partials
constexpr size_t OFF_SH  = 34612224;   // f16 [32][256][256] state
constexpr size_t OFF_O1  = 38806528;   // f16 [4096][256]

struct W7 { const float* W[7]; const float* b[7]; };

// Swizzled [R][64]-f16 tile helpers: rows are 128B = 8 granules of 16B;
// granule column XOR'ed with (row&7)  (T2 / G4 pattern, conflict-free b128).
__device__ __forceinline__ int toff(int row, int oct) {
    return row * 128 + (((oct) ^ (row & 7)) << 4);
}
__device__ __forceinline__ f16x8 ldfrag(const f16* base, int row, int oct) {
    return *(const f16x8*)((const char*)base + toff(row, oct));
}
__device__ __forceinline__ void stfrag(f16* base, int row, int oct, f16x8 v) {
    *(f16x8*)((char*)base + toff(row, oct)) = v;
}
// C/D layout of mfma_f32_32x32x16: col = lane&31, row = (reg&3)+8*(reg>>2)+4*(lane>>5)
__device__ __forceinline__ int drow(int reg, int l) {
    return (reg & 3) + ((reg >> 2) << 3) + ((l >> 5) << 2);
}
__device__ __forceinline__ void zero16(f32x16& v) {
#pragma unroll
    for (int i = 0; i < 16; ++i) v[i] = 0.f;
}

// ---------------- k_prep: conversions + W+I + scale + LN-fold prep ----------
__global__ __launch_bounds__(256) void k_prep(const float* __restrict__ x, W7 p,
                                              float scale,
                                              const float* __restrict__ Wo,
                                              const float* __restrict__ bo,
                                              const float* __restrict__ gamma,
                                              const float* __restrict__ beta,
                                              char* ws) {
    const int bid = blockIdx.x;
    if (bid < 2824) {
        f16* xh  = (f16*)(ws + OFF_XH);
        f16* Wh  = (f16*)(ws + OFF_WH);
        float* bsc = (float*)(ws + OFF_BSC);
        int idx = bid * 256 + threadIdx.x;
        if (idx < 262144) {                        // x -> xh
            float4 v = ((const float4*)x)[idx];
            f16x4 o; o[0] = (f16)v.x; o[1] = (f16)v.y; o[2] = (f16)v.z; o[3] = (f16)v.w;
            *(f16x4*)(xh + (size_t)idx * 4) = o;
        } else if (idx < 262144 + 458752) {        // W' = (W+I)*(t>=3?scale:1)
            int r = idx - 262144;
            int t = r >> 16, cc = r & 65535, c = cc >> 8, k = cc & 255;
            float v = p.W[t][cc] + (c == k ? 1.f : 0.f);
            if (t >= 3) v *= scale;
            Wh[r] = (f16)v;
        } else if (idx < 262144 + 458752 + 1792) { // scaled bias
            int r = idx - 262144 - 458752;
            int t = r >> 8;
            bsc[r] = p.b[t][r & 255] * (t >= 3 ? scale : 1.f);
        }
    } else {                                       // LN-fold
        f16* Gh = (f16*)(ws + OFF_GH);
        float* rsg = (float*)(ws + OFF_RSG);
        float* B2  = (float*)(ws + OFF_B2);
        int c2 = bid - 2824, c = threadIdx.x;
        float wv = Wo[c2 * 256 + c];
        float g = gamma[c] * wv;
        float bb = beta[c] * wv;
        Gh[c2 * 256 + c] = (f16)g;
        __shared__ float sg[4], sb[4];
#pragma unroll
        for (int off = 32; off > 0; off >>= 1) { g += __shfl_down(g, off); bb += __shfl_down(bb, off); }
        if ((c & 63) == 0) { sg[c >> 6] = g; sb[c >> 6] = bb; }
        __syncthreads();
        if (c == 0) {
            rsg[c2] = sg[0] + sg[1] + sg[2] + sg[3];
            B2[c2]  = sb[0] + sb[1] + sb[2] + sb[3] + bo[c2];
        }
    }
}

// ---------------- k_lin7: 7 fused linears via MFMA (512 thr, 8 waves) -------
// t<3 : D[n][c] = xh @ W'^T  -> Yq[t] row-major
// t>=3: D[c][n] = W' @ xh^T  -> Kt[t-3][b*16+h][d][n]
__global__ __launch_bounds__(512) void k_lin7(const float* __restrict__ mask, char* ws) {
    const f16* xh = (const f16*)(ws + OFF_XH);
    const f16* Wh = (const f16*)(ws + OFF_WH);
    const float* bsc = (const float*)(ws + OFF_BSC);
    f16* Yq = (f16*)(ws + OFF_YQ);
    f16* Kt = (f16*)(ws + OFF_KT);

    const int ct = blockIdx.x;            // 0..13
    const int rt = blockIdx.y;            // 0..31
    const int t = ct >> 1, half = ct & 1;
    const bool swap = (t >= 3);
    const int tid = threadIdx.x, l = tid & 63, w = tid >> 6;
    const int wr = w >> 1, wc = w & 1;    // wave tile: 32 rows x 64 cols

    __shared__ f16 Xl[128 * 64];
    __shared__ f16 Wl[128 * 64];

    f32x16 acc[2];
    zero16(acc[0]); zero16(acc[1]);

    const f16* Wt = Wh + (size_t)t * 65536;
    for (int kt = 0; kt < 4; ++kt) {
        __syncthreads();
#pragma unroll
        for (int e = 0; e < 2; ++e) {
            int g = tid + 512 * e;        // 0..1023
            int row = g >> 3, oct = g & 7;
            f16x8 vx = *(const f16x8*)(xh + (size_t)(rt * 128 + row) * 256 + kt * 64 + oct * 8);
            stfrag(Xl, row, oct, vx);
            f16x8 vw = *(const f16x8*)(Wt + (size_t)(half * 128 + row) * 256 + kt * 64 + oct * 8);
            stfrag(Wl, row, oct, vw);
        }
        __syncthreads();
        const f16* Ab = swap ? Wl : Xl;
        const f16* Bb = swap ? Xl : Wl;
#pragma unroll
        for (int s = 0; s < 4; ++s) {
            int g = s * 2 + (l >> 5);
            f16x8 a0 = ldfrag(Ab, wr * 32 + (l & 31), g);
            f16x8 b0 = ldfrag(Bb, wc * 64 + (l & 31), g);
            f16x8 b1 = ldfrag(Bb, wc * 64 + 32 + (l & 31), g);
            acc[0] = MFMA32(a0, b0, acc[0]);
            acc[1] = MFMA32(a0, b1, acc[1]);
        }
    }

#pragma unroll
    for (int mc = 0; mc < 2; ++mc)
#pragma unroll
        for (int reg = 0; reg < 16; ++reg) {
            int rowl = wr * 32 + drow(reg, l);
            int coll = wc * 64 + mc * 32 + (l & 31);
            if (!swap) {
                int n = rt * 128 + rowl;
                int c = half * 128 + coll;
                float v = (acc[mc][reg] + bsc[t * 256 + c]) * mask[n];
                Yq[(size_t)t * 1048576 + (size_t)n * 256 + c] = (f16)v;
            } else {
                int c = half * 128 + rowl;
                int n = rt * 128 + coll;
                float v = (acc[mc][reg] + bsc[t * 256 + c]) * mask[n];
                int tn = t - 3, bb = n >> 11, h = c >> 4, d = c & 15;
                Kt[(((size_t)tn * 32 + bb * 16 + h) * 16 + d) * 2048 + (n & 2047)] = (f16)v;
            }
        }
}

// ---------------- k_state: state = P^T Q (512 thr, 8 waves) -----------------
// Block: 128 ij (tr half) x 256 kl, split-K=4 (512 n each). f16 partials.
__global__ __launch_bounds__(512) void k_state(char* ws) {
    const f16* Kt = (const f16*)(ws + OFF_KT);
    f16* Sp = (f16*)(ws + OFF_SP);

    const int tr = blockIdx.x;            // 0..1  ij half
    const int bh = blockIdx.y;            // 0..31
    const int ks = blockIdx.z;            // 0..3  split-K
    const int tid = threadIdx.x, l = tid & 63, w = tid >> 6;
    const int wr = w >> 2, wc = w & 3;    // wave tile: 64 ij x 64 kl

    __shared__ f16 raw[2][64 * 64];       // dbuf [k1|k2|k3|v][16 d][64 n] swizzled

    f32x16 acc[2][2];
#pragma unroll
    for (int m = 0; m < 2; ++m)
#pragma unroll
        for (int mc = 0; mc < 2; ++mc) zero16(acc[m][mc]);

    const int nb0 = ks * 512;
    auto gaddr = [&](int g, int nb) -> const f16x8* {
        int t4 = g >> 7, d = (g >> 3) & 15, oct = g & 7;
        return (const f16x8*)(Kt + (((size_t)t4 * 32 + bh) * 16 + d) * 2048 + nb + oct * 8);
    };
    const int rowS = (tid >> 7) * 16 + ((tid >> 3) & 15);   // covers all 64 rows
    const int octS = tid & 7;

    f16x8 pre = *gaddr(tid, nb0);
    stfrag(raw[0], rowS, octS, pre);
    __syncthreads();

    int cur = 0;
    for (int kt = 0; kt < 8; ++kt) {
        if (kt < 7) pre = *gaddr(tid, nb0 + (kt + 1) * 64);
        const f16* rb = raw[cur];
#pragma unroll
        for (int s = 0; s < 4; ++s) {
            const int og = s * 2 + (l >> 5);
            f16x8 a[2], b[2];
#pragma unroll
            for (int m = 0; m < 2; ++m) {
                int rloc = wr * 64 + m * 32 + (l & 31);
                // P[ij] = k1[i] * v[j]: raw rows 0..15 = k1, 48..63 = v
                a[m] = ldfrag(rb, tr * 8 + (rloc >> 4), og) * ldfrag(rb, 48 + (rloc & 15), og);
            }
#pragma unroll
            for (int mc = 0; mc < 2; ++mc) {
                int cloc = wc * 64 + mc * 32 + (l & 31);
                // Q[kl] = k2[k] * k3[lv]: raw rows 16..31 = k2, 32..47 = k3
                b[mc] = ldfrag(rb, 16 + (cloc >> 4), og) * ldfrag(rb, 32 + (cloc & 15), og);
            }
#pragma unroll
            for (int m = 0; m < 2; ++m)
#pragma unroll
                for (int mc = 0; mc < 2; ++mc)
                    acc[m][mc] = MFMA32(a[m], b[mc], acc[m][mc]);
        }
        if (kt < 7) stfrag(raw[cur ^ 1], rowS, octS, pre);
        __syncthreads();
        cur ^= 1;
    }

    f16* outp = Sp + ((size_t)ks * 32 + bh) * 65536;
#pragma unroll
    for (int m = 0; m < 2; ++m)
#pragma unroll
        for (int mc = 0; mc < 2; ++mc)
#pragma unroll
            for (int reg = 0; reg < 16; ++reg) {
                int ij = tr * 128 + wr * 64 + m * 32 + drow(reg, l);
                int kl = wc * 64 + mc * 32 + (l & 31);
                outp[ij * 256 + kl] = (f16)acc[m][mc][reg];
            }
}

// ---------------- k_sred: sum 4 f16 split-K partials -> f16 state -----------
__global__ __launch_bounds__(256) void k_sred(char* ws) {
    const f16x8* Sp = (const f16x8*)(ws + OFF_SP);
    f16x8* Sh = (f16x8*)(ws + OFF_SH);
    int i = blockIdx.x * 256 + threadIdx.x;     // granule index, 262144 total
    f16x8 a = Sp[i], b = Sp[262144 + i], c = Sp[524288 + i], d = Sp[786432 + i];
    Sh[i] = (a + b) + (c + d);
}

// ---------------- k_out1: T = U @ S^T (register-direct U) + q1 contraction --
__global__ __launch_bounds__(256, 2) void k_out1(char* ws) {
    const f16* Yq = (const f16*)(ws + OFF_YQ);
    const f16* Sh = (const f16*)(ws + OFF_SH);
    f16* O1 = (f16*)(ws + OFF_O1);

    const int ntile = blockIdx.x;         // 0..15
    const int bh = blockIdx.y;
    const int b = bh >> 4, hb = (bh & 15) * 16;
    const int n0 = ntile * 128;
    const int tid = threadIdx.x, l = tid & 63, w = tid >> 6;
    const int wn = w >> 1, wc = w & 1;    // wave tile: 64 n x 128 ij

    __shared__ f16 Sl[2][256 * 64];       // state tile dbuf (64KB)
    __shared__ f16 Ql[128 * 64];          // per row: [q1 0-15][q2 16-31][q3 32-47][pad]
    float* part = (float*)Sl;             // epilogue overlay [4][64][16] f32

    // stage Ql (octs 0..5 hold q1,q2,q3; 6,7 unused)
#pragma unroll
    for (int e = 0; e < 4; ++e) {
        int g = tid + 256 * e;
        int row = g >> 3, oct = g & 7;
        if (oct < 6) {
            int t = oct >> 1, hf = oct & 1;
            f16x8 v = *(const f16x8*)(Yq + (size_t)t * 1048576 +
                                      (size_t)(b * 2048 + n0 + row) * 256 + hb + hf * 8);
            stfrag(Ql, row, oct, v);
        }
    }
    // stage Sl[0]
    const int qrow = tid >> 3, qoct = tid & 7;
    f16x8 pre[8];
#pragma unroll
    for (int e = 0; e < 8; ++e)
        pre[e] = *(const f16x8*)(Sh + (size_t)bh * 65536 + (size_t)(qrow + 32 * e) * 256 + qoct * 8);
#pragma unroll
    for (int e = 0; e < 8; ++e) stfrag(Sl[0], qrow + 32 * e, qoct, pre[e]);
    __syncthreads();

    f32x16 acc[2][4];
#pragma unroll
    for (int m = 0; m < 2; ++m)
#pragma unroll
        for (int fc = 0; fc < 4; ++fc) zero16(acc[m][fc]);

    int cur = 0;
    for (int kt = 0; kt < 4; ++kt) {
        if (kt < 3) {
#pragma unroll
            for (int e = 0; e < 8; ++e)
                pre[e] = *(const f16x8*)(Sh + (size_t)bh * 65536 +
                                         (size_t)(qrow + 32 * e) * 256 + (kt + 1) * 64 + qoct * 8);
        }
        const f16* sb = Sl[cur];
#pragma unroll
        for (int s = 0; s < 4; ++s) {
            const int og = s * 2 + (l >> 5);
            const int kq = kt * 4 + s;        // global q2 column
            f16x8 a[2];
#pragma unroll
            for (int m = 0; m < 2; ++m) {
                int nloc = wn * 64 + m * 32 + (l & 31);
                f16x8 q3 = ldfrag(Ql, nloc, 4 + (og & 1));
                f16 q2 = *(const f16*)((const char*)Ql + toff(nloc, 2 + (kq >> 3)) + (kq & 7) * 2);
                a[m] = q3 * q2;
            }
#pragma unroll
            for (int fc = 0; fc < 4; ++fc) {
                f16x8 bf = ldfrag(sb, wc * 128 + fc * 32 + (l & 31), og);
                acc[0][fc] = MFMA32(a[0], bf, acc[0][fc]);
                acc[1][fc] = MFMA32(a[1], bf, acc[1][fc]);
            }
        }
        if (kt < 3) {
#pragma unroll
            for (int e = 0; e < 8; ++e) stfrag(Sl[cur ^ 1], qrow + 32 * e, qoct, pre[e]);
        }
        __syncthreads();
        cur ^= 1;
    }

    // epilogue: out[n][j] = sum_i q1[n][i] * T[n][i*16+j]
    const int hi = (l & 31) >> 4;
#pragma unroll
    for (int m = 0; m < 2; ++m)
#pragma unroll
        for (int reg = 0; reg < 16; ++reg) {
            int nloc = wn * 64 + m * 32 + drow(reg, l);
            f16x8 q1v = ldfrag(Ql, nloc, wc);     // q1 elems [8*wc .. 8*wc+8)
            float val = 0.f;
#pragma unroll
            for (int fc = 0; fc < 4; ++fc) {
                float qv = hi ? (float)q1v[2 * fc + 1] : (float)q1v[2 * fc];
                val += qv * acc[m][fc][reg];
            }
            val += __shfl_xor(val, 16);
            if ((l & 16) == 0)
                part[((wn * 2 + wc) * 64 + (nloc & 63)) * 16 + (l & 15)] = val;
        }
    __syncthreads();
    {
        int nloc = tid >> 1, jb = (tid & 1) * 8;
        int wnb = nloc >> 6, nr = nloc & 63;
        f16x8 o;
#pragma unroll
        for (int e = 0; e < 8; ++e) {
            int j = jb + e;
            o[e] = (f16)(part[((wnb * 2 + 0) * 64 + nr) * 16 + j] +
                         part[((wnb * 2 + 1) * 64 + nr) * 16 + j]);
        }
        *(f16x8*)(O1 + (size_t)(b * 2048 + n0 + nloc) * 256 + hb + jb) = o;
    }
}

// ---------------- k_final: out = LN(O1) @ Wo^T + bo, stats fused ------------
__global__ __launch_bounds__(256) void k_final(float* __restrict__ out, char* ws) {
    const f16* O1 = (const f16*)(ws + OFF_O1);
    const f16* Gh = (const f16*)(ws + OFF_GH);
    const float* rsg = (const float*)(ws + OFF_RSG);
    const float* B2 = (const float*)(ws + OFF_B2);

    const int ct = blockIdx.x;            // 0..1
    const int rt = blockIdx.y;            // 0..31
    const int tid = threadIdx.x, l = tid & 63, w = tid >> 6;
    const int wr = w >> 1, wc = w & 1;

    __shared__ f16 Xl[128 * 64];
    __shared__ f16 Wl[128 * 64];
    __shared__ float muL[128], rsL[128];

    float sum[4] = {0.f, 0.f, 0.f, 0.f}, sumsq[4] = {0.f, 0.f, 0.f, 0.f};

    f32x16 acc[2][2];
#pragma unroll
    for (int m = 0; m < 2; ++m)
#pragma unroll
        for (int mc = 0; mc < 2; ++mc) zero16(acc[m][mc]);

    for (int kt = 0; kt < 4; ++kt) {
        __syncthreads();
#pragma unroll
        for (int e = 0; e < 4; ++e) {
            int g = tid + 256 * e;
            int row = g >> 3, oct = g & 7;
            f16x8 vx = *(const f16x8*)(O1 + (size_t)(rt * 128 + row) * 256 + kt * 64 + oct * 8);
            stfrag(Xl, row, oct, vx);
#pragma unroll
            for (int q = 0; q < 8; ++q) { float f = (float)vx[q]; sum[e] += f; sumsq[e] += f * f; }
            f16x8 vw = *(const f16x8*)(Gh + (size_t)(ct * 128 + row) * 256 + kt * 64 + oct * 8);
            stfrag(Wl, row, oct, vw);
        }
        __syncthreads();
#pragma unroll
        for (int s = 0; s < 4; ++s) {
            int g = s * 2 + (l >> 5);
            f16x8 a0 = ldfrag(Xl, wr * 64 + (l & 31), g);
            f16x8 a1 = ldfrag(Xl, wr * 64 + 32 + (l & 31), g);
            f16x8 b0 = ldfrag(Wl, wc * 64 + (l & 31), g);
            f16x8 b1 = ldfrag(Wl, wc * 64 + 32 + (l & 31), g);
            acc[0][0] = MFMA32(a0, b0, acc[0][0]);
            acc[0][1] = MFMA32(a0, b1, acc[0][1]);
            acc[1][0] = MFMA32(a1, b0, acc[1][0]);
            acc[1][1] = MFMA32(a1, b1, acc[1][1]);
        }
    }

    // row stats: 8 threads (same tid>>3) share each row
#pragma unroll
    for (int e = 0; e < 4; ++e) {
#pragma unroll
        for (int off = 1; off < 8; off <<= 1) {
            sum[e] += __shfl_xor(sum[e], off);
            sumsq[e] += __shfl_xor(sumsq[e], off);
        }
    }
    if ((tid & 7) == 0) {
#pragma unroll
        for (int e = 0; e < 4; ++e) {
            int row = (tid >> 3) + 32 * e;
            float m = sum[e] * (1.f / 256.f);
            float var = sumsq[e] * (1.f / 256.f) - m * m;
            muL[row] = m;
            rsL[row] = rsqrtf(var + 1e-5f);
        }
    }
    __syncthreads();

#pragma unroll
    for (int m = 0; m < 2; ++m)
#pragma unroll
        for (int mc = 0; mc < 2; ++mc)
#pragma unroll
            for (int reg = 0; reg < 16; ++reg) {
                int nloc = wr * 64 + m * 32 + drow(reg, l);
                int n = rt * 128 + nloc;
                int c2 = ct * 128 + wc * 64 + mc * 32 + (l & 31);
                float v = rsL[nloc] * (acc[m][mc][reg] - muL[nloc] * rsg[c2]) + B2[c2];
                out[(size_t)n * 256 + c2] = v;
            }
}

// ---------------------------------------------------------------------------
extern "C" void kernel_launch(void* const* d_in, const int* in_sizes, int n_in,
                              void* d_out, int out_size, void* d_ws, size_t ws_size,
                              hipStream_t stream) {
    (void)in_sizes; (void)n_in; (void)out_size; (void)ws_size;
    const float* x    = (const float*)d_in[0];
    const float* mask = (const float*)d_in[1];
    W7 p;
    for (int t = 0; t < 7; ++t) {
        p.W[t] = (const float*)d_in[2 + 2 * t];
        p.b[t] = (const float*)d_in[3 + 2 * t];
    }
    const float* Wo    = (const float*)d_in[16];
    const float* bo    = (const float*)d_in[17];
    const float* gamma = (const float*)d_in[18];
    const float* beta  = (const float*)d_in[19];
    char* ws = (char*)d_ws;

    const float scale = 0.14865088937534013f;   // 2048^(-0.25)

    k_prep <<<3080, 256, 0, stream>>>(x, p, scale, Wo, bo, gamma, beta, ws);
    k_lin7 <<<dim3(14, 32), 512, 0, stream>>>(mask, ws);
    k_state<<<dim3(2, 32, 4), 512, 0, stream>>>(ws);
    k_sred <<<1024, 256, 0, stream>>>(ws);
    k_out1 <<<dim3(16, 32), 256, 0, stream>>>(ws);
    k_final<<<dim3(2, 32), 256, 0, stream>>>((float*)d_out, ws);
}